// Round 1
// baseline (5460.806 us; speedup 1.0000x reference)
//
#include <hip/hip_runtime.h>
#include <math.h>

#define N_TOK 8192
#define DIM   768
#define MEMN  10000
#define TQ    32
#define TM    256
#define DKC   32
#define NSPLIT 2
#define TILES_PER_SPLIT 20   // ceil(10000/256)=40 tiles, 20 per split

constexpr float SCALE = 0.036084391824351615f;  // 1/sqrt(768)

// ---------------------------------------------------------------------------
// Fused attention: O_partial[split] = sum_m exp(Q.mem_m * SCALE) * mem_m
//                  L_partial[split] = sum_m exp(...)
// No max-subtraction needed: logits ~ N(0,1), |logit| <= ~6, exp safe in fp32.
// ---------------------------------------------------------------------------
__global__ __launch_bounds__(256, 2)
void attn_kernel(const float* __restrict__ Q, const float* __restrict__ Mem,
                 float* __restrict__ Opart, float* __restrict__ Lpart)
{
    __shared__ __align__(16) float Qs[DKC][TQ + 4];    // transposed [d][q]
    __shared__ __align__(16) float Ks[DKC][TM + 4];    // transposed [d][m]
    __shared__ __align__(16) float Ps[TQ][TM + 4];     // [q][m]

    const int tid   = threadIdx.x;
    const int q0    = blockIdx.x * TQ;
    const int split = blockIdx.y;

    // phase-1 mapping: S[32 q][256 m], per thread 4q x 8m
    const int p1_tq = tid >> 5;          // 0..7  -> q = 4*p1_tq + qq
    const int p1_tm = tid & 31;          // 0..31 -> m = 8*p1_tm + mm
    // phase-2 mapping: O[32 q][768 d], per thread 8q x 12d, wave = fixed tq
    const int p2_tq = tid >> 6;          // 0..3  -> q = 8*p2_tq + qq
    const int p2_td = tid & 63;          // 0..63 -> d = 12*p2_td + j

    float oacc[8][12];
    float lsum[8];
#pragma unroll
    for (int i = 0; i < 8; ++i) {
        lsum[i] = 0.f;
#pragma unroll
        for (int j = 0; j < 12; ++j) oacc[i][j] = 0.f;
    }

    const int qs_row = tid >> 3;          // 0..31
    const int qs_d4  = (tid & 7) * 4;     // 0,4,...,28

    const int kt_begin = split * TILES_PER_SPLIT;
    const int kt_end   = kt_begin + TILES_PER_SPLIT;

    for (int kt = kt_begin; kt < kt_end; ++kt) {
        const int m0 = kt * TM;

        float s[4][8];
#pragma unroll
        for (int a = 0; a < 4; ++a)
#pragma unroll
            for (int b = 0; b < 8; ++b) s[a][b] = 0.f;

        // ---- phase 1: S = Q * K^T over d in chunks of 32 ----
        for (int dc = 0; dc < DIM; dc += DKC) {
            __syncthreads();
            {   // stage Q chunk (32q x 32d), transposed
                float4 v = *(const float4*)&Q[(size_t)(q0 + qs_row) * DIM + dc + qs_d4];
                Qs[qs_d4 + 0][qs_row] = v.x;
                Qs[qs_d4 + 1][qs_row] = v.y;
                Qs[qs_d4 + 2][qs_row] = v.z;
                Qs[qs_d4 + 3][qs_row] = v.w;
            }
#pragma unroll
            for (int i = 0; i < 8; ++i) {   // stage K chunk (256m x 32d), transposed
                int f    = tid + i * 256;
                int mrow = f >> 3;
                int d4   = (f & 7) * 4;
                int mg   = m0 + mrow;
                float4 v = make_float4(0.f, 0.f, 0.f, 0.f);
                if (mg < MEMN) v = *(const float4*)&Mem[(size_t)mg * DIM + dc + d4];
                Ks[d4 + 0][mrow] = v.x;
                Ks[d4 + 1][mrow] = v.y;
                Ks[d4 + 2][mrow] = v.z;
                Ks[d4 + 3][mrow] = v.w;
            }
            __syncthreads();
#pragma unroll 8
            for (int d = 0; d < DKC; ++d) {
                float4 qv = *(const float4*)&Qs[d][p1_tq * 4];
                float4 k0 = *(const float4*)&Ks[d][p1_tm * 8];
                float4 k1 = *(const float4*)&Ks[d][p1_tm * 8 + 4];
                float qa[4] = {qv.x, qv.y, qv.z, qv.w};
                float ka[8] = {k0.x, k0.y, k0.z, k0.w, k1.x, k1.y, k1.z, k1.w};
#pragma unroll
                for (int a = 0; a < 4; ++a)
#pragma unroll
                    for (int b = 0; b < 8; ++b)
                        s[a][b] += qa[a] * ka[b];
            }
        }

        // ---- exp + store P (masked for m >= MEMN) ----
#pragma unroll
        for (int qq = 0; qq < 4; ++qq) {
            float pv[8];
#pragma unroll
            for (int b = 0; b < 8; ++b) {
                int mg = m0 + p1_tm * 8 + b;
                pv[b] = (mg < MEMN) ? __expf(s[qq][b] * SCALE) : 0.f;
            }
            *(float4*)&Ps[p1_tq * 4 + qq][p1_tm * 8]     = make_float4(pv[0], pv[1], pv[2], pv[3]);
            *(float4*)&Ps[p1_tq * 4 + qq][p1_tm * 8 + 4] = make_float4(pv[4], pv[5], pv[6], pv[7]);
        }
        __syncthreads();

        // ---- phase 2: O += P * Mem, Mem rows streamed from global (L1/L2 reuse) ----
        const float* mp = Mem + (size_t)m0 * DIM + p2_td * 12;
        float4 b0 = *(const float4*)(mp);
        float4 b1 = *(const float4*)(mp + 4);
        float4 b2 = *(const float4*)(mp + 8);
        for (int mm = 0; mm < TM; ++mm) {
            int mn = m0 + mm + 1;
            if (mn >= MEMN) mn = MEMN - 1;      // clamp: P=0 there anyway
            const float* np = Mem + (size_t)mn * DIM + p2_td * 12;
            float4 n0 = *(const float4*)(np);
            float4 n1 = *(const float4*)(np + 4);
            float4 n2 = *(const float4*)(np + 8);
            float p[8];
#pragma unroll
            for (int qq = 0; qq < 8; ++qq) {
                p[qq] = Ps[p2_tq * 8 + qq][mm];   // broadcast read
                lsum[qq] += p[qq];
            }
#pragma unroll
            for (int qq = 0; qq < 8; ++qq) {
                oacc[qq][0]  += p[qq] * b0.x;
                oacc[qq][1]  += p[qq] * b0.y;
                oacc[qq][2]  += p[qq] * b0.z;
                oacc[qq][3]  += p[qq] * b0.w;
                oacc[qq][4]  += p[qq] * b1.x;
                oacc[qq][5]  += p[qq] * b1.y;
                oacc[qq][6]  += p[qq] * b1.z;
                oacc[qq][7]  += p[qq] * b1.w;
                oacc[qq][8]  += p[qq] * b2.x;
                oacc[qq][9]  += p[qq] * b2.y;
                oacc[qq][10] += p[qq] * b2.z;
                oacc[qq][11] += p[qq] * b2.w;
            }
            b0 = n0; b1 = n1; b2 = n2;
        }
    }

    // ---- epilogue: write partials ----
#pragma unroll
    for (int qq = 0; qq < 8; ++qq) {
        int row = q0 + p2_tq * 8 + qq;
        float* ob = Opart + ((size_t)split * N_TOK + row) * DIM + p2_td * 12;
        *(float4*)(ob)     = make_float4(oacc[qq][0], oacc[qq][1], oacc[qq][2],  oacc[qq][3]);
        *(float4*)(ob + 4) = make_float4(oacc[qq][4], oacc[qq][5], oacc[qq][6],  oacc[qq][7]);
        *(float4*)(ob + 8) = make_float4(oacc[qq][8], oacc[qq][9], oacc[qq][10], oacc[qq][11]);
        if (p2_td == 0) Lpart[split * N_TOK + row] = lsum[qq];
    }
}

// ---------------------------------------------------------------------------
// Combine partials, normalize, compute gate, store retrieved + g.
// One wave per row (4 rows per 256-thread block).
// ---------------------------------------------------------------------------
__global__ __launch_bounds__(256)
void reduce_gate_kernel(const float* __restrict__ Opart, const float* __restrict__ Lpart,
                        const float* __restrict__ cs, const float* __restrict__ gw,
                        const float* __restrict__ gb,
                        float* __restrict__ retr, float* __restrict__ gvec)
{
    const int lane = threadIdx.x & 63;
    const int row  = blockIdx.x * 4 + (threadIdx.x >> 6);
    const float l  = Lpart[row] + Lpart[N_TOK + row];
    const float rl = 1.0f / l;
    const float* o0 = Opart + (size_t)row * DIM;
    const float* o1 = Opart + ((size_t)N_TOK + row) * DIM;
    const float* cr = cs + (size_t)row * DIM;

    float rv[12];
    float d1 = 0.f, d2 = 0.f;
#pragma unroll
    for (int i = 0; i < 12; ++i) {
        int c = lane + 64 * i;
        float r = (o0[c] + o1[c]) * rl;
        rv[i] = r;
        d1 += cr[c] * gw[c];
        d2 += r * gw[DIM + c];
    }
    float g = d1 + d2;
#pragma unroll
    for (int off = 32; off > 0; off >>= 1) g += __shfl_xor(g, off);
    g += gb[0];
    g = 1.0f / (1.0f + __expf(-g));

    float* rr = retr + (size_t)row * DIM;
#pragma unroll
    for (int i = 0; i < 12; ++i) rr[lane + 64 * i] = rv[i];
    if (lane == 0) gvec[row] = g;
}

// ---------------------------------------------------------------------------
// W1s = W1[0:768,:] + W1[768:1536,:]   (fold the duplicated x slices)
// ---------------------------------------------------------------------------
__global__ void prep_w1s(const float* __restrict__ w1, float* __restrict__ w1s)
{
    int i = (blockIdx.x * 256 + threadIdx.x) * 4;
    float4 a = *(const float4*)&w1[i];
    float4 b = *(const float4*)&w1[589824 + i];
    *(float4*)&w1s[i] = make_float4(a.x + b.x, a.y + b.y, a.z + b.z, a.w + b.w);
}

// ---------------------------------------------------------------------------
// MLP GEMM, tile = 16 rows x 768 cols, 256 threads (4 waves x 64 lanes).
// MODE 0: h = gelu(x@W1s + r@W1c + b1), where x = cs + g*r built during staging.
// MODE 1: out = LayerNorm(h@W2 + b2) * gamma + beta (LN fused: wave owns rows).
// ---------------------------------------------------------------------------
template <int MODE>
__global__ __launch_bounds__(256, 2)
void mlp_kernel(const float* __restrict__ A1, const float* __restrict__ W1,
                const float* __restrict__ A2, const float* __restrict__ W2,
                const float* __restrict__ bias, const float* __restrict__ gvec,
                const float* __restrict__ gamma, const float* __restrict__ beta,
                float* __restrict__ out)
{
    __shared__ __align__(16) float As[16][20];        // transposed [k][row]
    __shared__ __align__(16) float Ws[16][DIM + 8];   // [k][col]

    const int tid = threadIdx.x;
    const int r0  = blockIdx.x * 16;
    const int tq  = tid >> 6;     // 0..3 -> rows 4*tq+a
    const int td  = tid & 63;     // cols 12*td+b

    float acc[4][12];
#pragma unroll
    for (int a = 0; a < 4; ++a)
#pragma unroll
        for (int b = 0; b < 12; ++b) acc[a][b] = 0.f;

    const int nsrc = (MODE == 0) ? 2 : 1;
    for (int src = 0; src < nsrc; ++src) {
        const float* A = src ? A2 : A1;
        const float* W = src ? W2 : W1;
        for (int kc = 0; kc < DIM; kc += 16) {
            __syncthreads();
            if (tid < 64) {   // stage A chunk 16 rows x 16 k, transposed
                int row = tid >> 2, k4 = (tid & 3) * 4;
                float4 v = *(const float4*)&A[(size_t)(r0 + row) * DIM + kc + k4];
                if (MODE == 0 && src == 0) {   // x = cs + g * retr on the fly
                    float g = gvec[r0 + row];
                    float4 r = *(const float4*)&A2[(size_t)(r0 + row) * DIM + kc + k4];
                    v.x += g * r.x; v.y += g * r.y; v.z += g * r.z; v.w += g * r.w;
                }
                As[k4 + 0][row] = v.x;
                As[k4 + 1][row] = v.y;
                As[k4 + 2][row] = v.z;
                As[k4 + 3][row] = v.w;
            }
#pragma unroll
            for (int i = 0; i < 12; ++i) {   // stage W chunk 16 k x 768 cols
                int f  = tid + i * 256;      // float4 index
                int kr = f / 192;
                int c4 = (f - kr * 192) * 4;
                float4 v = *(const float4*)&W[(size_t)(kc + kr) * DIM + c4];
                *(float4*)&Ws[kr][c4] = v;
            }
            __syncthreads();
#pragma unroll
            for (int k = 0; k < 16; ++k) {
                float4 av = *(const float4*)&As[k][tq * 4];    // broadcast in wave
                float4 w0 = *(const float4*)&Ws[k][td * 12];
                float4 w1 = *(const float4*)&Ws[k][td * 12 + 4];
                float4 w2 = *(const float4*)&Ws[k][td * 12 + 8];
                float aa[4]  = {av.x, av.y, av.z, av.w};
                float ww[12] = {w0.x, w0.y, w0.z, w0.w, w1.x, w1.y, w1.z, w1.w,
                                w2.x, w2.y, w2.z, w2.w};
#pragma unroll
                for (int a = 0; a < 4; ++a)
#pragma unroll
                    for (int b = 0; b < 12; ++b)
                        acc[a][b] += aa[a] * ww[b];
            }
        }
    }

    float4 t0 = *(const float4*)&bias[td * 12];
    float4 t1 = *(const float4*)&bias[td * 12 + 4];
    float4 t2 = *(const float4*)&bias[td * 12 + 8];
    float bv[12] = {t0.x, t0.y, t0.z, t0.w, t1.x, t1.y, t1.z, t1.w, t2.x, t2.y, t2.z, t2.w};

    if (MODE == 0) {
#pragma unroll
        for (int a = 0; a < 4; ++a) {
            int row = r0 + tq * 4 + a;
            float vv[12];
#pragma unroll
            for (int b = 0; b < 12; ++b) {
                float v = acc[a][b] + bv[b];
                vv[b] = 0.5f * v * (1.0f + erff(v * 0.7071067811865476f));
            }
            float* ob = out + (size_t)row * DIM + td * 12;
            *(float4*)(ob)     = make_float4(vv[0], vv[1], vv[2],  vv[3]);
            *(float4*)(ob + 4) = make_float4(vv[4], vv[5], vv[6],  vv[7]);
            *(float4*)(ob + 8) = make_float4(vv[8], vv[9], vv[10], vv[11]);
        }
    } else {
        float4 g0 = *(const float4*)&gamma[td * 12];
        float4 g1 = *(const float4*)&gamma[td * 12 + 4];
        float4 g2 = *(const float4*)&gamma[td * 12 + 8];
        float4 e0 = *(const float4*)&beta[td * 12];
        float4 e1 = *(const float4*)&beta[td * 12 + 4];
        float4 e2 = *(const float4*)&beta[td * 12 + 8];
        float gv[12] = {g0.x, g0.y, g0.z, g0.w, g1.x, g1.y, g1.z, g1.w, g2.x, g2.y, g2.z, g2.w};
        float ev[12] = {e0.x, e0.y, e0.z, e0.w, e1.x, e1.y, e1.z, e1.w, e2.x, e2.y, e2.z, e2.w};
#pragma unroll
        for (int a = 0; a < 4; ++a) {
            float v[12];
            float s1 = 0.f, s2 = 0.f;
#pragma unroll
            for (int b = 0; b < 12; ++b) {
                v[b] = acc[a][b] + bv[b];
                s1 += v[b];
                s2 += v[b] * v[b];
            }
#pragma unroll
            for (int off = 32; off > 0; off >>= 1) {
                s1 += __shfl_xor(s1, off);
                s2 += __shfl_xor(s2, off);
            }
            float mu  = s1 * (1.0f / 768.0f);
            float var = fmaxf(s2 * (1.0f / 768.0f) - mu * mu, 0.f);
            float rs  = rsqrtf(var + 1e-5f);
            int row = r0 + tq * 4 + a;
            float ov[12];
#pragma unroll
            for (int b = 0; b < 12; ++b)
                ov[b] = (v[b] - mu) * rs * gv[b] + ev[b];
            float* ob = out + (size_t)row * DIM + td * 12;
            *(float4*)(ob)     = make_float4(ov[0], ov[1], ov[2],  ov[3]);
            *(float4*)(ob + 4) = make_float4(ov[4], ov[5], ov[6],  ov[7]);
            *(float4*)(ob + 8) = make_float4(ov[8], ov[9], ov[10], ov[11]);
        }
    }
}

// ---------------------------------------------------------------------------
extern "C" void kernel_launch(void* const* d_in, const int* in_sizes, int n_in,
                              void* d_out, int out_size, void* d_ws, size_t ws_size,
                              hipStream_t stream)
{
    const float* cs  = (const float*)d_in[0];
    const float* mem = (const float*)d_in[1];
    const float* gw  = (const float*)d_in[2];
    const float* gb  = (const float*)d_in[3];
    const float* fw1 = (const float*)d_in[4];
    const float* fb1 = (const float*)d_in[5];
    const float* fw2 = (const float*)d_in[6];
    const float* fb2 = (const float*)d_in[7];
    const float* gam = (const float*)d_in[8];
    const float* bet = (const float*)d_in[9];
    float* out = (float*)d_out;

    float* ws = (float*)d_ws;
    const size_t ND = (size_t)N_TOK * DIM;
    float* Opart = ws;                       // 2*ND   (50.3 MB)
    float* Lpart = Opart + 2 * ND;           // 2*N
    float* rbuf  = Lpart + 2 * N_TOK;        // ND     (25.2 MB)
    float* gvec  = rbuf + ND;                // N
    float* w1s   = gvec + N_TOK;             // 589824 (2.4 MB)
    float* hbuf  = Opart;                    // alias: Opart dead after reduce
    // total ws: ~78 MB

    prep_w1s<<<576, 256, 0, stream>>>(fw1, w1s);
    attn_kernel<<<dim3(N_TOK / TQ, NSPLIT), 256, 0, stream>>>(cs, mem, Opart, Lpart);
    reduce_gate_kernel<<<N_TOK / 4, 256, 0, stream>>>(Opart, Lpart, cs, gw, gb, rbuf, gvec);
    mlp_kernel<0><<<N_TOK / 16, 256, 0, stream>>>(cs, w1s, rbuf, fw1 + 2 * 589824, fb1,
                                                  gvec, nullptr, nullptr, hbuf);
    mlp_kernel<1><<<N_TOK / 16, 256, 0, stream>>>(hbuf, fw2, nullptr, nullptr, fb2,
                                                  nullptr, gam, bet, out);
}

// Round 3
// 2257.206 us; speedup vs baseline: 2.4193x; 2.4193x over previous
//
#include <hip/hip_runtime.h>
#include <math.h>

#define N_TOK 8192
#define DIM   768
#define MEMN  10000
#define MEMP  10240            // padded to 40*256
#define TQ    32
#define TM    256
#define NTILES 40              // 40*256 = 10240 m (padded)

constexpr float SCALE = 0.036084391824351615f;  // 1/sqrt(768)

typedef short bf16x8 __attribute__((ext_vector_type(8)));
typedef float f32x4  __attribute__((ext_vector_type(4)));

__device__ __forceinline__ unsigned short f2bf(float f) {
    unsigned u = __float_as_uint(f);
    unsigned r = (u + 0x7fffu + ((u >> 16) & 1u)) >> 16;   // RTN-even
    return (unsigned short)r;
}

// ---------------------------------------------------------------------------
// mem fp32 [10000][768] -> memH bf16 [10240][768], padded rows zero.
// ---------------------------------------------------------------------------
__global__ void cvt_memH(const float* __restrict__ mem, unsigned short* __restrict__ dst)
{
    const int m = blockIdx.x;
    const int d = threadIdx.x * 4;
    float4 v = make_float4(0.f, 0.f, 0.f, 0.f);
    if (m < MEMN) v = *(const float4*)&mem[(size_t)m * DIM + d];
    ushort4 o;
    o.x = f2bf(v.x); o.y = f2bf(v.y); o.z = f2bf(v.z); o.w = f2bf(v.w);
    *(ushort4*)&dst[(size_t)m * DIM + d] = o;
}

// ---------------------------------------------------------------------------
// memT bf16 [768][10240]: memT[d][m] = mem[m][d] (0 for m>=10000)
// ---------------------------------------------------------------------------
__global__ void transpose_mem(const float* __restrict__ mem, unsigned short* __restrict__ memT)
{
    __shared__ float T[32][33];
    const int mb = blockIdx.x * 32, db = blockIdx.y * 32;
    const int tx = threadIdx.x & 31, ty = threadIdx.x >> 5;   // ty 0..7
#pragma unroll
    for (int i = 0; i < 4; ++i) {
        int m = mb + ty + 8 * i;
        T[ty + 8 * i][tx] = (m < MEMN) ? mem[(size_t)m * DIM + db + tx] : 0.f;
    }
    __syncthreads();
#pragma unroll
    for (int i = 0; i < 4; ++i) {
        int d = ty + 8 * i;
        memT[(size_t)(db + d) * MEMP + mb + tx] = f2bf(T[tx][d]);
    }
}

// ---------------------------------------------------------------------------
// Fused MFMA attention, single-split: block = 32 q-rows x ALL 40 m-tiles.
// Phase 1: S = Q*Mem^T (16x16x32 bf16 MFMA, B-frags direct from memH).
// exp (logits ~N(0,1): no max-subtraction needed); P -> double-buffered
// swizzled LDS (ONE barrier per tile); row-sums in registers.
// Phase 2: O += P*Mem (B-frags direct from memT).
// Epilogue: normalize by row-sum (block-wide reduce) and write retrieved.
// ---------------------------------------------------------------------------
__global__ __launch_bounds__(256, 2)
void attn_mfma(const float* __restrict__ Q, const unsigned short* __restrict__ memH,
               const unsigned short* __restrict__ memT,
               float* __restrict__ retr)
{
    __shared__ __align__(16) unsigned short Qs[32 * 768];       // 48 KB, xor-swizzled
    __shared__ __align__(16) unsigned short Ps[2][32 * 256];    // 2x16 KB, xor-swizzled
    __shared__ float Lred[4][32];

    const int tid   = threadIdx.x;
    const int w     = tid >> 6;         // wave 0..3
    const int lane  = tid & 63;
    const int quad  = lane >> 4;        // 0..3
    const int l16   = lane & 15;
    const int q0    = blockIdx.x * TQ;
    const int dbase = w * 192;          // phase-2 d-range per wave

    // ---- stage Q tile (fp32 -> bf16, swizzled) once ----
    {
        const int qr  = tid >> 3;            // 0..31
        const int db0 = tid & 7;
        const float* src = Q + (size_t)(q0 + qr) * DIM;
        const int sw = qr & 7;
#pragma unroll
        for (int i = 0; i < 12; ++i) {
            int db = db0 + i * 8;            // 0..95 (blocks of 8 bf16)
            float4 v0 = *(const float4*)&src[db * 8];
            float4 v1 = *(const float4*)&src[db * 8 + 4];
            uint4 o;
            o.x = (unsigned)f2bf(v0.x) | ((unsigned)f2bf(v0.y) << 16);
            o.y = (unsigned)f2bf(v0.z) | ((unsigned)f2bf(v0.w) << 16);
            o.z = (unsigned)f2bf(v1.x) | ((unsigned)f2bf(v1.y) << 16);
            o.w = (unsigned)f2bf(v1.z) | ((unsigned)f2bf(v1.w) << 16);
            *(uint4*)&Qs[qr * 768 + ((db ^ sw) << 3)] = o;
        }
    }
    __syncthreads();

    f32x4 oacc[2][12];
#pragma unroll
    for (int a = 0; a < 2; ++a)
#pragma unroll
        for (int b = 0; b < 12; ++b) oacc[a][b] = (f32x4){0.f, 0.f, 0.f, 0.f};
    float lsum[2][4] = {{0.f, 0.f, 0.f, 0.f}, {0.f, 0.f, 0.f, 0.f}};

    const int xsw = l16 & 7;

    for (int st = 0; st < NTILES; ++st) {
        const int m0  = st * TM;
        const int buf = st & 1;

        // ---- phase 1: S[32 x 256]; wave w covers m-strip w*64..+64 ----
        f32x4 sacc[2][4];
#pragma unroll
        for (int a = 0; a < 2; ++a)
#pragma unroll
            for (int b = 0; b < 4; ++b) sacc[a][b] = (f32x4){0.f, 0.f, 0.f, 0.f};

        const unsigned short* brow = memH + (size_t)(m0 + w * 64 + l16) * DIM;

        for (int kc = 0; kc < DIM; kc += 32) {
            const int xq = (((kc >> 3) + quad) ^ xsw) << 3;
            bf16x8 a0 = *(const bf16x8*)&Qs[l16 * 768 + xq];
            bf16x8 a1 = *(const bf16x8*)&Qs[(16 + l16) * 768 + xq];
#pragma unroll
            for (int mt = 0; mt < 4; ++mt) {
                bf16x8 bb = *(const bf16x8*)(brow + (size_t)mt * 16 * DIM + kc + quad * 8);
                sacc[0][mt] = __builtin_amdgcn_mfma_f32_16x16x32_bf16(a0, bb, sacc[0][mt], 0, 0, 0);
                sacc[1][mt] = __builtin_amdgcn_mfma_f32_16x16x32_bf16(a1, bb, sacc[1][mt], 0, 0, 0);
            }
        }

        // ---- exp + P->LDS[buf] (bf16, swizzled) + row-sum accumulation ----
        // WAR on Ps[buf] vs tile st-2 readers is ordered by the st-1 barrier.
#pragma unroll
        for (int qt = 0; qt < 2; ++qt)
#pragma unroll
            for (int mt = 0; mt < 4; ++mt) {
                const int mloc = w * 64 + mt * 16 + l16;      // 0..255
                const bool ok  = (m0 + mloc) < MEMN;
#pragma unroll
                for (int r = 0; r < 4; ++r) {
                    float p = ok ? __expf(sacc[qt][mt][r] * SCALE) : 0.f;
                    const int q = qt * 16 + quad * 4 + r;
                    lsum[qt][r] += p;
                    Ps[buf][q * 256 + (((mloc >> 3) ^ (q & 7)) << 3) + (mloc & 7)] = f2bf(p);
                }
            }

        __syncthreads();   // the ONE barrier per tile: P[buf] complete

        // ---- phase 2: O += P * Mem; wave w covers d-range dbase..+192 ----
        for (int kc = 0; kc < TM; kc += 32) {
            const int xp = (((kc >> 3) + quad) ^ xsw) << 3;
            bf16x8 pa0 = *(const bf16x8*)&Ps[buf][l16 * 256 + xp];
            bf16x8 pa1 = *(const bf16x8*)&Ps[buf][(16 + l16) * 256 + xp];
            const unsigned short* mtp = memT + (size_t)(dbase + l16) * MEMP + m0 + kc + quad * 8;
#pragma unroll
            for (int nt = 0; nt < 12; ++nt) {
                bf16x8 mb = *(const bf16x8*)(mtp + (size_t)nt * 16 * MEMP);
                oacc[0][nt] = __builtin_amdgcn_mfma_f32_16x16x32_bf16(pa0, mb, oacc[0][nt], 0, 0, 0);
                oacc[1][nt] = __builtin_amdgcn_mfma_f32_16x16x32_bf16(pa1, mb, oacc[1][nt], 0, 0, 0);
            }
        }
        // no trailing barrier: next tile's phase 1 doesn't touch Ps
    }

    // ---- block-wide row-sum reduction ----
#pragma unroll
    for (int qt = 0; qt < 2; ++qt)
#pragma unroll
        for (int r = 0; r < 4; ++r) {
            float v = lsum[qt][r];
#pragma unroll
            for (int off = 1; off < 16; off <<= 1) v += __shfl_xor(v, off);
            if (l16 == 0) Lred[w][qt * 16 + quad * 4 + r] = v;
        }
    __syncthreads();

    // ---- normalize + write retrieved ----
    float* ob = retr + (size_t)q0 * DIM;
#pragma unroll
    for (int qt = 0; qt < 2; ++qt) {
        float rl[4];
#pragma unroll
        for (int r = 0; r < 4; ++r) {
            int ql = qt * 16 + quad * 4 + r;
            rl[r] = 1.0f / (Lred[0][ql] + Lred[1][ql] + Lred[2][ql] + Lred[3][ql]);
        }
#pragma unroll
        for (int nt = 0; nt < 12; ++nt)
#pragma unroll
            for (int r = 0; r < 4; ++r)
                ob[(size_t)(qt * 16 + quad * 4 + r) * DIM + dbase + nt * 16 + l16] =
                    oacc[qt][nt][r] * rl[r];
    }
}

// ---------------------------------------------------------------------------
// Gate: g = sigmoid([cs, retr] @ gate_w + gate_b). One wave per row.
// ---------------------------------------------------------------------------
__global__ __launch_bounds__(256)
void gate_kernel(const float* __restrict__ cs, const float* __restrict__ retr,
                 const float* __restrict__ gw, const float* __restrict__ gb,
                 float* __restrict__ gvec)
{
    const int lane = threadIdx.x & 63;
    const int row  = blockIdx.x * 4 + (threadIdx.x >> 6);
    const float* cr = cs + (size_t)row * DIM;
    const float* rr = retr + (size_t)row * DIM;
    float g = 0.f;
#pragma unroll
    for (int i = 0; i < 12; ++i) {
        int c = lane + 64 * i;
        g += cr[c] * gw[c] + rr[c] * gw[DIM + c];
    }
#pragma unroll
    for (int off = 32; off > 0; off >>= 1) g += __shfl_xor(g, off);
    g += gb[0];
    g = 1.0f / (1.0f + __expf(-g));
    if (lane == 0) gvec[row] = g;
}

// ---------------------------------------------------------------------------
__global__ void prep_w1s(const float* __restrict__ w1, float* __restrict__ w1s)
{
    int i = (blockIdx.x * 256 + threadIdx.x) * 4;
    float4 a = *(const float4*)&w1[i];
    float4 b = *(const float4*)&w1[589824 + i];
    *(float4*)&w1s[i] = make_float4(a.x + b.x, a.y + b.y, a.z + b.z, a.w + b.w);
}

// ---------------------------------------------------------------------------
// MLP GEMM (fp32 VALU), tile = 16 rows x 768 cols, 256 threads.
// MODE 0: h = gelu(x@W1s + r@W1c + b1), x = cs + g*r built during staging.
// MODE 1: out = LayerNorm(h@W2 + b2)*gamma + beta (LN fused, wave owns rows).
// ---------------------------------------------------------------------------
template <int MODE>
__global__ __launch_bounds__(256, 2)
void mlp_kernel(const float* __restrict__ A1, const float* __restrict__ W1,
                const float* __restrict__ A2, const float* __restrict__ W2,
                const float* __restrict__ bias, const float* __restrict__ gvec,
                const float* __restrict__ gamma, const float* __restrict__ beta,
                float* __restrict__ out)
{
    __shared__ __align__(16) float As[16][20];
    __shared__ __align__(16) float Ws[16][DIM + 8];

    const int tid = threadIdx.x;
    const int r0  = blockIdx.x * 16;
    const int tq  = tid >> 6;
    const int td  = tid & 63;

    float acc[4][12];
#pragma unroll
    for (int a = 0; a < 4; ++a)
#pragma unroll
        for (int b = 0; b < 12; ++b) acc[a][b] = 0.f;

    const int nsrc = (MODE == 0) ? 2 : 1;
    for (int src = 0; src < nsrc; ++src) {
        const float* A = src ? A2 : A1;
        const float* W = src ? W2 : W1;
        for (int kc = 0; kc < DIM; kc += 16) {
            __syncthreads();
            if (tid < 64) {
                int row = tid >> 2, k4 = (tid & 3) * 4;
                float4 v = *(const float4*)&A[(size_t)(r0 + row) * DIM + kc + k4];
                if (MODE == 0 && src == 0) {
                    float g = gvec[r0 + row];
                    float4 r = *(const float4*)&A2[(size_t)(r0 + row) * DIM + kc + k4];
                    v.x += g * r.x; v.y += g * r.y; v.z += g * r.z; v.w += g * r.w;
                }
                As[k4 + 0][row] = v.x;
                As[k4 + 1][row] = v.y;
                As[k4 + 2][row] = v.z;
                As[k4 + 3][row] = v.w;
            }
#pragma unroll
            for (int i = 0; i < 12; ++i) {
                int f  = tid + i * 256;
                int kr = f / 192;
                int c4 = (f - kr * 192) * 4;
                float4 v = *(const float4*)&W[(size_t)(kc + kr) * DIM + c4];
                *(float4*)&Ws[kr][c4] = v;
            }
            __syncthreads();
#pragma unroll
            for (int k = 0; k < 16; ++k) {
                float4 av = *(const float4*)&As[k][tq * 4];
                float4 w0 = *(const float4*)&Ws[k][td * 12];
                float4 w1 = *(const float4*)&Ws[k][td * 12 + 4];
                float4 w2 = *(const float4*)&Ws[k][td * 12 + 8];
                float aa[4]  = {av.x, av.y, av.z, av.w};
                float ww[12] = {w0.x, w0.y, w0.z, w0.w, w1.x, w1.y, w1.z, w1.w,
                                w2.x, w2.y, w2.z, w2.w};
#pragma unroll
                for (int a = 0; a < 4; ++a)
#pragma unroll
                    for (int b = 0; b < 12; ++b)
                        acc[a][b] += aa[a] * ww[b];
            }
        }
    }

    float4 t0 = *(const float4*)&bias[td * 12];
    float4 t1 = *(const float4*)&bias[td * 12 + 4];
    float4 t2 = *(const float4*)&bias[td * 12 + 8];
    float bv[12] = {t0.x, t0.y, t0.z, t0.w, t1.x, t1.y, t1.z, t1.w, t2.x, t2.y, t2.z, t2.w};

    if (MODE == 0) {
#pragma unroll
        for (int a = 0; a < 4; ++a) {
            int row = r0 + tq * 4 + a;
            float vv[12];
#pragma unroll
            for (int b = 0; b < 12; ++b) {
                float v = acc[a][b] + bv[b];
                vv[b] = 0.5f * v * (1.0f + erff(v * 0.7071067811865476f));
            }
            float* ob = out + (size_t)row * DIM + td * 12;
            *(float4*)(ob)     = make_float4(vv[0], vv[1], vv[2],  vv[3]);
            *(float4*)(ob + 4) = make_float4(vv[4], vv[5], vv[6],  vv[7]);
            *(float4*)(ob + 8) = make_float4(vv[8], vv[9], vv[10], vv[11]);
        }
    } else {
        float4 g0 = *(const float4*)&gamma[td * 12];
        float4 g1 = *(const float4*)&gamma[td * 12 + 4];
        float4 g2 = *(const float4*)&gamma[td * 12 + 8];
        float4 e0 = *(const float4*)&beta[td * 12];
        float4 e1 = *(const float4*)&beta[td * 12 + 4];
        float4 e2 = *(const float4*)&beta[td * 12 + 8];
        float gv[12] = {g0.x, g0.y, g0.z, g0.w, g1.x, g1.y, g1.z, g1.w, g2.x, g2.y, g2.z, g2.w};
        float ev[12] = {e0.x, e0.y, e0.z, e0.w, e1.x, e1.y, e1.z, e1.w, e2.x, e2.y, e2.z, e2.w};
#pragma unroll
        for (int a = 0; a < 4; ++a) {
            float v[12];
            float s1 = 0.f, s2 = 0.f;
#pragma unroll
            for (int b = 0; b < 12; ++b) {
                v[b] = acc[a][b] + bv[b];
                s1 += v[b];
                s2 += v[b] * v[b];
            }
#pragma unroll
            for (int off = 32; off > 0; off >>= 1) {
                s1 += __shfl_xor(s1, off);
                s2 += __shfl_xor(s2, off);
            }
            float mu  = s1 * (1.0f / 768.0f);
            float var = fmaxf(s2 * (1.0f / 768.0f) - mu * mu, 0.f);
            float rs  = rsqrtf(var + 1e-5f);
            int row = r0 + tq * 4 + a;
            float ov[12];
#pragma unroll
            for (int b = 0; b < 12; ++b)
                ov[b] = (v[b] - mu) * rs * gv[b] + ev[b];
            float* ob = out + (size_t)row * DIM + td * 12;
            *(float4*)(ob)     = make_float4(ov[0], ov[1], ov[2],  ov[3]);
            *(float4*)(ob + 4) = make_float4(ov[4], ov[5], ov[6],  ov[7]);
            *(float4*)(ob + 8) = make_float4(ov[8], ov[9], ov[10], ov[11]);
        }
    }
}

// ---------------------------------------------------------------------------
extern "C" void kernel_launch(void* const* d_in, const int* in_sizes, int n_in,
                              void* d_out, int out_size, void* d_ws, size_t ws_size,
                              hipStream_t stream)
{
    const float* cs  = (const float*)d_in[0];
    const float* mem = (const float*)d_in[1];
    const float* gw  = (const float*)d_in[2];
    const float* gb  = (const float*)d_in[3];
    const float* fw1 = (const float*)d_in[4];
    const float* fb1 = (const float*)d_in[5];
    const float* fw2 = (const float*)d_in[6];
    const float* fb2 = (const float*)d_in[7];
    const float* gam = (const float*)d_in[8];
    const float* bet = (const float*)d_in[9];
    float* out = (float*)d_out;

    char* ws = (char*)d_ws;
    // layout (bytes), total ~56.3 MB (round-1's 78 MB ran clean):
    unsigned short* memH = (unsigned short*)ws;                 // 15,728,640
    unsigned short* memT = (unsigned short*)(ws + 15728640);    // 15,728,640
    float* retr = (float*)(ws + 31457280);                      // 25,165,824
    float* gvec = (float*)(ws + 56623104);                      // 32,768
    float* w1s  = (float*)(ws + 56655872);                      // 2,359,296 -> end 59,015,168
    float* hbuf = (float*)ws;   // alias memH+memT (dead after attn), 25.2 MB

    cvt_memH<<<MEMP, 192, 0, stream>>>(mem, memH);
    transpose_mem<<<dim3(MEMP / 32, DIM / 32), 256, 0, stream>>>(mem, memT);
    prep_w1s<<<576, 256, 0, stream>>>(fw1, w1s);

    attn_mfma<<<N_TOK / TQ, 256, 0, stream>>>(cs, memH, memT, retr);
    gate_kernel<<<N_TOK / 4, 256, 0, stream>>>(cs, retr, gw, gb, gvec);
    mlp_kernel<0><<<N_TOK / 16, 256, 0, stream>>>(cs, w1s, retr, fw1 + 2 * 589824, fb1,
                                                  gvec, nullptr, nullptr, hbuf);
    mlp_kernel<1><<<N_TOK / 16, 256, 0, stream>>>(hbuf, fw2, nullptr, nullptr, fb2,
                                                  nullptr, gam, bet, out);
}

// Round 4
// 1542.990 us; speedup vs baseline: 3.5391x; 1.4629x over previous
//
#include <hip/hip_runtime.h>
#include <math.h>

#define N_TOK 8192
#define DIM   768
#define MEMN  10000
#define MEMP  10240            // padded to 40*256
#define TQ    32
#define TM    256
#define NSPLIT 2
#define TILES_PER_SPLIT 20

constexpr float SCALE = 0.036084391824351615f;  // 1/sqrt(768)

typedef short bf16x8 __attribute__((ext_vector_type(8)));
typedef float f32x4  __attribute__((ext_vector_type(4)));

__device__ __forceinline__ unsigned short f2bf(float f) {
    unsigned u = __float_as_uint(f);
    unsigned r = (u + 0x7fffu + ((u >> 16) & 1u)) >> 16;   // RTN-even
    return (unsigned short)r;
}

// ---------------------------------------------------------------------------
// mem fp32 [10000][768] -> memH bf16 [10240][768], padded rows zero.
// ---------------------------------------------------------------------------
__global__ void cvt_memH(const float* __restrict__ mem, unsigned short* __restrict__ dst)
{
    const int m = blockIdx.x;
    const int d = threadIdx.x * 4;
    float4 v = make_float4(0.f, 0.f, 0.f, 0.f);
    if (m < MEMN) v = *(const float4*)&mem[(size_t)m * DIM + d];
    ushort4 o;
    o.x = f2bf(v.x); o.y = f2bf(v.y); o.z = f2bf(v.z); o.w = f2bf(v.w);
    *(ushort4*)&dst[(size_t)m * DIM + d] = o;
}

// ---------------------------------------------------------------------------
// memT bf16 [768][10240]: memT[d][m] = mem[m][d] (0 for m>=10000)
// ---------------------------------------------------------------------------
__global__ void transpose_mem(const float* __restrict__ mem, unsigned short* __restrict__ memT)
{
    __shared__ float T[32][33];
    const int mb = blockIdx.x * 32, db = blockIdx.y * 32;
    const int tx = threadIdx.x & 31, ty = threadIdx.x >> 5;   // ty 0..7
#pragma unroll
    for (int i = 0; i < 4; ++i) {
        int m = mb + ty + 8 * i;
        T[ty + 8 * i][tx] = (m < MEMN) ? mem[(size_t)m * DIM + db + tx] : 0.f;
    }
    __syncthreads();
#pragma unroll
    for (int i = 0; i < 4; ++i) {
        int d = ty + 8 * i;
        memT[(size_t)(db + d) * MEMP + mb + tx] = f2bf(T[tx][d]);
    }
}

// ---------------------------------------------------------------------------
// Fused MFMA attention, 2-way m-split, 512-thread blocks (8 waves).
// Per block: 32 q-rows x 20 m-tiles. LDS = Qs 48K + Ps 16K = 64.5K -> 2 blk/CU,
// 16 waves/CU. All fragments software-pipelined one iteration ahead.
// Splits combine via agent-scope fp32 atomicAdd into zero-init'd retr/Lvec.
// ---------------------------------------------------------------------------
__global__ __launch_bounds__(512, 4)
void attn_mfma(const float* __restrict__ Q, const unsigned short* __restrict__ memH,
               const unsigned short* __restrict__ memT,
               float* __restrict__ retrRaw, float* __restrict__ Lvec)
{
    __shared__ __align__(16) unsigned short Qs[32 * 768];   // 48 KB, xor-swizzled
    __shared__ __align__(16) unsigned short Ps[32 * 256];   // 16 KB, xor-swizzled

    const int tid    = threadIdx.x;
    const int w      = tid >> 6;         // wave 0..7
    const int lane   = tid & 63;
    const int quad   = lane >> 4;        // 0..3
    const int l16    = lane & 15;
    const int q0     = blockIdx.x * TQ;
    const int split  = blockIdx.y;
    const int dbase  = w * 96;           // phase-2 d-strip per wave
    const int mstrip = w * 32;           // phase-1 m-strip per wave

    // ---- stage Q tile (fp32 -> bf16, swizzled) once ----
    {
        const int qr  = tid >> 4;            // 0..31
        const int db0 = tid & 15;
        const float* src = Q + (size_t)(q0 + qr) * DIM;
        const int sw = qr & 7;
#pragma unroll
        for (int i = 0; i < 6; ++i) {
            int db = db0 + i * 16;           // 0..95 (blocks of 8 bf16)
            float4 v0 = *(const float4*)&src[db * 8];
            float4 v1 = *(const float4*)&src[db * 8 + 4];
            uint4 o;
            o.x = (unsigned)f2bf(v0.x) | ((unsigned)f2bf(v0.y) << 16);
            o.y = (unsigned)f2bf(v0.z) | ((unsigned)f2bf(v0.w) << 16);
            o.z = (unsigned)f2bf(v1.x) | ((unsigned)f2bf(v1.y) << 16);
            o.w = (unsigned)f2bf(v1.z) | ((unsigned)f2bf(v1.w) << 16);
            *(uint4*)&Qs[qr * 768 + ((db ^ sw) << 3)] = o;
        }
    }
    __syncthreads();

    f32x4 oacc[2][6];
#pragma unroll
    for (int a = 0; a < 2; ++a)
#pragma unroll
        for (int b = 0; b < 6; ++b) oacc[a][b] = (f32x4){0.f, 0.f, 0.f, 0.f};
    float lsum[2][4] = {{0.f, 0.f, 0.f, 0.f}, {0.f, 0.f, 0.f, 0.f}};

    const int xsw = l16 & 7;

    for (int st = 0; st < TILES_PER_SPLIT; ++st) {
        const int m0 = (split * TILES_PER_SPLIT + st) * TM;

        // ---- phase 1: S[32 x 256]; wave w covers m-strip mstrip..+32 ----
        f32x4 sacc[2][2];
#pragma unroll
        for (int a = 0; a < 2; ++a)
#pragma unroll
            for (int b = 0; b < 2; ++b) sacc[a][b] = (f32x4){0.f, 0.f, 0.f, 0.f};

        const unsigned short* brow = memH + (size_t)(m0 + mstrip + l16) * DIM + quad * 8;

        bf16x8 b0 = *(const bf16x8*)(brow);
        bf16x8 b1 = *(const bf16x8*)(brow + 16 * DIM);
        {
            const int xq0 = ((quad) ^ xsw) << 3;
            bf16x8 a0 = *(const bf16x8*)&Qs[l16 * 768 + xq0];
            bf16x8 a1 = *(const bf16x8*)&Qs[(16 + l16) * 768 + xq0];
            for (int kc = 0; kc < DIM; kc += 32) {
                int nk = kc + 32; if (nk == DIM) nk = 0;
                // prefetch next iteration's fragments
                bf16x8 nb0 = *(const bf16x8*)(brow + nk);
                bf16x8 nb1 = *(const bf16x8*)(brow + 16 * DIM + nk);
                const int xq = (((nk >> 3) + quad) ^ xsw) << 3;
                bf16x8 na0 = *(const bf16x8*)&Qs[l16 * 768 + xq];
                bf16x8 na1 = *(const bf16x8*)&Qs[(16 + l16) * 768 + xq];
                sacc[0][0] = __builtin_amdgcn_mfma_f32_16x16x32_bf16(a0, b0, sacc[0][0], 0, 0, 0);
                sacc[1][0] = __builtin_amdgcn_mfma_f32_16x16x32_bf16(a1, b0, sacc[1][0], 0, 0, 0);
                sacc[0][1] = __builtin_amdgcn_mfma_f32_16x16x32_bf16(a0, b1, sacc[0][1], 0, 0, 0);
                sacc[1][1] = __builtin_amdgcn_mfma_f32_16x16x32_bf16(a1, b1, sacc[1][1], 0, 0, 0);
                a0 = na0; a1 = na1; b0 = nb0; b1 = nb1;
            }
        }

        __syncthreads();   // barrier A: all waves done reading previous tile's Ps

        // ---- exp + P->LDS (bf16, swizzled) + row-sum accumulation ----
#pragma unroll
        for (int qt = 0; qt < 2; ++qt)
#pragma unroll
            for (int mt = 0; mt < 2; ++mt) {
                const int mloc = mstrip + mt * 16 + l16;      // 0..255
                const bool ok  = (m0 + mloc) < MEMN;
#pragma unroll
                for (int r = 0; r < 4; ++r) {
                    float p = ok ? __expf(sacc[qt][mt][r] * SCALE) : 0.f;
                    const int q = qt * 16 + quad * 4 + r;
                    lsum[qt][r] += p;
                    Ps[q * 256 + (((mloc >> 3) ^ (q & 7)) << 3) + (mloc & 7)] = f2bf(p);
                }
            }

        __syncthreads();   // barrier B: Ps complete

        // ---- phase 2: O += P * Mem; wave w covers d-strip dbase..+96 ----
        const unsigned short* mtp = memT + (size_t)(dbase + l16) * MEMP + m0 + quad * 8;
        bf16x8 c[6];
#pragma unroll
        for (int nt = 0; nt < 6; ++nt)
            c[nt] = *(const bf16x8*)(mtp + (size_t)nt * 16 * MEMP);

        {
            const int xp0 = ((quad) ^ xsw) << 3;
            bf16x8 pa0 = *(const bf16x8*)&Ps[l16 * 256 + xp0];
            bf16x8 pa1 = *(const bf16x8*)&Ps[(16 + l16) * 256 + xp0];
            for (int kc = 0; kc < TM; kc += 32) {
                int nk = kc + 32; if (nk == TM) nk = 0;
                const int xp = (((nk >> 3) + quad) ^ xsw) << 3;
                bf16x8 npa0 = *(const bf16x8*)&Ps[l16 * 256 + xp];
                bf16x8 npa1 = *(const bf16x8*)&Ps[(16 + l16) * 256 + xp];
#pragma unroll
                for (int nt = 0; nt < 6; ++nt) {
                    oacc[0][nt] = __builtin_amdgcn_mfma_f32_16x16x32_bf16(pa0, c[nt], oacc[0][nt], 0, 0, 0);
                    oacc[1][nt] = __builtin_amdgcn_mfma_f32_16x16x32_bf16(pa1, c[nt], oacc[1][nt], 0, 0, 0);
                    // reload this slot for the next kc right after its last use
                    c[nt] = *(const bf16x8*)(mtp + (size_t)nt * 16 * MEMP + nk);
                }
                pa0 = npa0; pa1 = npa1;
            }
        }
        // no trailing barrier: next tile's phase 1 doesn't touch Ps
    }

    // ---- epilogue: atomically combine O and L across splits ----
#pragma unroll
    for (int qt = 0; qt < 2; ++qt)
#pragma unroll
        for (int nt = 0; nt < 6; ++nt)
#pragma unroll
            for (int r = 0; r < 4; ++r)
                __hip_atomic_fetch_add(
                    &retrRaw[(size_t)(q0 + qt * 16 + quad * 4 + r) * DIM + dbase + nt * 16 + l16],
                    oacc[qt][nt][r], __ATOMIC_RELAXED, __HIP_MEMORY_SCOPE_AGENT);

#pragma unroll
    for (int qt = 0; qt < 2; ++qt)
#pragma unroll
        for (int r = 0; r < 4; ++r) {
            float v = lsum[qt][r];
#pragma unroll
            for (int off = 1; off < 16; off <<= 1) v += __shfl_xor(v, off);
            if (l16 == 0)
                __hip_atomic_fetch_add(&Lvec[q0 + qt * 16 + quad * 4 + r], v,
                                       __ATOMIC_RELAXED, __HIP_MEMORY_SCOPE_AGENT);
        }
}

// ---------------------------------------------------------------------------
// Normalize retrieved in place + gate. One wave per row.
// ---------------------------------------------------------------------------
__global__ __launch_bounds__(256)
void finalize_gate(float* __restrict__ retr, const float* __restrict__ Lvec,
                   const float* __restrict__ cs, const float* __restrict__ gw,
                   const float* __restrict__ gb, float* __restrict__ gvec)
{
    const int lane = threadIdx.x & 63;
    const int row  = blockIdx.x * 4 + (threadIdx.x >> 6);
    const float rl = 1.0f / Lvec[row];
    float* rr = retr + (size_t)row * DIM;
    const float* cr = cs + (size_t)row * DIM;
    float g = 0.f;
#pragma unroll
    for (int i = 0; i < 12; ++i) {
        int c = lane + 64 * i;
        float r = rr[c] * rl;
        rr[c] = r;
        g += cr[c] * gw[c] + r * gw[DIM + c];
    }
#pragma unroll
    for (int off = 32; off > 0; off >>= 1) g += __shfl_xor(g, off);
    g += gb[0];
    g = 1.0f / (1.0f + __expf(-g));
    if (lane == 0) gvec[row] = g;
}

// ---------------------------------------------------------------------------
__global__ void prep_w1s(const float* __restrict__ w1, float* __restrict__ w1s)
{
    int i = (blockIdx.x * 256 + threadIdx.x) * 4;
    float4 a = *(const float4*)&w1[i];
    float4 b = *(const float4*)&w1[589824 + i];
    *(float4*)&w1s[i] = make_float4(a.x + b.x, a.y + b.y, a.z + b.z, a.w + b.w);
}

// ---------------------------------------------------------------------------
// MLP GEMM (fp32 VALU), tile = 16 rows x 768 cols, 256 threads.
// MODE 0: h = gelu(x@W1s + r@W1c + b1), x = cs + g*r built during staging.
// MODE 1: out = LayerNorm(h@W2 + b2)*gamma + beta (LN fused, wave owns rows).
// ---------------------------------------------------------------------------
template <int MODE>
__global__ __launch_bounds__(256, 2)
void mlp_kernel(const float* __restrict__ A1, const float* __restrict__ W1,
                const float* __restrict__ A2, const float* __restrict__ W2,
                const float* __restrict__ bias, const float* __restrict__ gvec,
                const float* __restrict__ gamma, const float* __restrict__ beta,
                float* __restrict__ out)
{
    __shared__ __align__(16) float As[16][20];
    __shared__ __align__(16) float Ws[16][DIM + 8];

    const int tid = threadIdx.x;
    const int r0  = blockIdx.x * 16;
    const int tq  = tid >> 6;
    const int td  = tid & 63;

    float acc[4][12];
#pragma unroll
    for (int a = 0; a < 4; ++a)
#pragma unroll
        for (int b = 0; b < 12; ++b) acc[a][b] = 0.f;

    const int nsrc = (MODE == 0) ? 2 : 1;
    for (int src = 0; src < nsrc; ++src) {
        const float* A = src ? A2 : A1;
        const float* W = src ? W2 : W1;
        for (int kc = 0; kc < DIM; kc += 16) {
            __syncthreads();
            if (tid < 64) {
                int row = tid >> 2, k4 = (tid & 3) * 4;
                float4 v = *(const float4*)&A[(size_t)(r0 + row) * DIM + kc + k4];
                if (MODE == 0 && src == 0) {
                    float g = gvec[r0 + row];
                    float4 r = *(const float4*)&A2[(size_t)(r0 + row) * DIM + kc + k4];
                    v.x += g * r.x; v.y += g * r.y; v.z += g * r.z; v.w += g * r.w;
                }
                As[k4 + 0][row] = v.x;
                As[k4 + 1][row] = v.y;
                As[k4 + 2][row] = v.z;
                As[k4 + 3][row] = v.w;
            }
#pragma unroll
            for (int i = 0; i < 12; ++i) {
                int f  = tid + i * 256;
                int kr = f / 192;
                int c4 = (f - kr * 192) * 4;
                float4 v = *(const float4*)&W[(size_t)(kc + kr) * DIM + c4];
                *(float4*)&Ws[kr][c4] = v;
            }
            __syncthreads();
#pragma unroll
            for (int k = 0; k < 16; ++k) {
                float4 av = *(const float4*)&As[k][tq * 4];
                float4 w0 = *(const float4*)&Ws[k][td * 12];
                float4 w1 = *(const float4*)&Ws[k][td * 12 + 4];
                float4 w2 = *(const float4*)&Ws[k][td * 12 + 8];
                float aa[4]  = {av.x, av.y, av.z, av.w};
                float ww[12] = {w0.x, w0.y, w0.z, w0.w, w1.x, w1.y, w1.z, w1.w,
                                w2.x, w2.y, w2.z, w2.w};
#pragma unroll
                for (int a = 0; a < 4; ++a)
#pragma unroll
                    for (int b = 0; b < 12; ++b)
                        acc[a][b] += aa[a] * ww[b];
            }
        }
    }

    float4 t0 = *(const float4*)&bias[td * 12];
    float4 t1 = *(const float4*)&bias[td * 12 + 4];
    float4 t2 = *(const float4*)&bias[td * 12 + 8];
    float bv[12] = {t0.x, t0.y, t0.z, t0.w, t1.x, t1.y, t1.z, t1.w, t2.x, t2.y, t2.z, t2.w};

    if (MODE == 0) {
#pragma unroll
        for (int a = 0; a < 4; ++a) {
            int row = r0 + tq * 4 + a;
            float vv[12];
#pragma unroll
            for (int b = 0; b < 12; ++b) {
                float v = acc[a][b] + bv[b];
                vv[b] = 0.5f * v * (1.0f + erff(v * 0.7071067811865476f));
            }
            float* ob = out + (size_t)row * DIM + td * 12;
            *(float4*)(ob)     = make_float4(vv[0], vv[1], vv[2],  vv[3]);
            *(float4*)(ob + 4) = make_float4(vv[4], vv[5], vv[6],  vv[7]);
            *(float4*)(ob + 8) = make_float4(vv[8], vv[9], vv[10], vv[11]);
        }
    } else {
        float4 g0 = *(const float4*)&gamma[td * 12];
        float4 g1 = *(const float4*)&gamma[td * 12 + 4];
        float4 g2 = *(const float4*)&gamma[td * 12 + 8];
        float4 e0 = *(const float4*)&beta[td * 12];
        float4 e1 = *(const float4*)&beta[td * 12 + 4];
        float4 e2 = *(const float4*)&beta[td * 12 + 8];
        float gv[12] = {g0.x, g0.y, g0.z, g0.w, g1.x, g1.y, g1.z, g1.w, g2.x, g2.y, g2.z, g2.w};
        float ev[12] = {e0.x, e0.y, e0.z, e0.w, e1.x, e1.y, e1.z, e1.w, e2.x, e2.y, e2.z, e2.w};
#pragma unroll
        for (int a = 0; a < 4; ++a) {
            float v[12];
            float s1 = 0.f, s2 = 0.f;
#pragma unroll
            for (int b = 0; b < 12; ++b) {
                v[b] = acc[a][b] + bv[b];
                s1 += v[b];
                s2 += v[b] * v[b];
            }
#pragma unroll
            for (int off = 32; off > 0; off >>= 1) {
                s1 += __shfl_xor(s1, off);
                s2 += __shfl_xor(s2, off);
            }
            float mu  = s1 * (1.0f / 768.0f);
            float var = fmaxf(s2 * (1.0f / 768.0f) - mu * mu, 0.f);
            float rs  = rsqrtf(var + 1e-5f);
            int row = r0 + tq * 4 + a;
            float ov[12];
#pragma unroll
            for (int b = 0; b < 12; ++b)
                ov[b] = (v[b] - mu) * rs * gv[b] + ev[b];
            float* ob = out + (size_t)row * DIM + td * 12;
            *(float4*)(ob)     = make_float4(ov[0], ov[1], ov[2],  ov[3]);
            *(float4*)(ob + 4) = make_float4(ov[4], ov[5], ov[6],  ov[7]);
            *(float4*)(ob + 8) = make_float4(ov[8], ov[9], ov[10], ov[11]);
        }
    }
}

// ---------------------------------------------------------------------------
extern "C" void kernel_launch(void* const* d_in, const int* in_sizes, int n_in,
                              void* d_out, int out_size, void* d_ws, size_t ws_size,
                              hipStream_t stream)
{
    const float* cs  = (const float*)d_in[0];
    const float* mem = (const float*)d_in[1];
    const float* gw  = (const float*)d_in[2];
    const float* gb  = (const float*)d_in[3];
    const float* fw1 = (const float*)d_in[4];
    const float* fb1 = (const float*)d_in[5];
    const float* fw2 = (const float*)d_in[6];
    const float* fb2 = (const float*)d_in[7];
    const float* gam = (const float*)d_in[8];
    const float* bet = (const float*)d_in[9];
    float* out = (float*)d_out;

    char* ws = (char*)d_ws;
    // layout (bytes), total ~59 MB (round-3's 59 MB ran clean):
    unsigned short* memH = (unsigned short*)ws;                 // 15,728,640
    unsigned short* memT = (unsigned short*)(ws + 15728640);    // 15,728,640
    float* retr = (float*)(ws + 31457280);                      // 25,165,824 (raw->normalized)
    float* Lvec = (float*)(ws + 56623104);                      // 32,768
    float* gvec = (float*)(ws + 56655872);                      // 32,768
    float* w1s  = (float*)(ws + 56688640);                      // 2,359,296 -> end 59,047,936
    float* hbuf = (float*)ws;   // alias memH+memT (dead after attn), 25.2 MB

    // zero-init atomic accumulation buffers (retr + Lvec are contiguous)
    hipMemsetAsync(retr, 0, (size_t)N_TOK * DIM * 4 + N_TOK * 4, stream);

    cvt_memH<<<MEMP, 192, 0, stream>>>(mem, memH);
    transpose_mem<<<dim3(MEMP / 32, DIM / 32), 256, 0, stream>>>(mem, memT);
    prep_w1s<<<576, 256, 0, stream>>>(fw1, w1s);

    attn_mfma<<<dim3(N_TOK / TQ, NSPLIT), 512, 0, stream>>>(cs, memH, memT, retr, Lvec);
    finalize_gate<<<N_TOK / 4, 256, 0, stream>>>(retr, Lvec, cs, gw, gb, gvec);
    mlp_kernel<0><<<N_TOK / 16, 256, 0, stream>>>(cs, w1s, retr, fw1 + 2 * 589824, fb1,
                                                  gvec, nullptr, nullptr, hbuf);
    mlp_kernel<1><<<N_TOK / 16, 256, 0, stream>>>(hbuf, fw2, nullptr, nullptr, fb2,
                                                  nullptr, gam, bet, out);
}

// Round 5
// 1534.071 us; speedup vs baseline: 3.5597x; 1.0058x over previous
//
#include <hip/hip_runtime.h>
#include <math.h>

#define N_TOK 8192
#define DIM   768
#define MEMN  10000
#define MEMP  10240            // padded to 40*256
#define TQ    32
#define TM    256
#define NSPLIT 2
#define TILES_PER_SPLIT 20

constexpr float SCALE = 0.036084391824351615f;  // 1/sqrt(768)

typedef short bf16x8 __attribute__((ext_vector_type(8)));
typedef float f32x4  __attribute__((ext_vector_type(4)));

__device__ __forceinline__ unsigned short f2bf(float f) {
    unsigned u = __float_as_uint(f);
    unsigned r = (u + 0x7fffu + ((u >> 16) & 1u)) >> 16;   // RTN-even
    return (unsigned short)r;
}

// ---------------------------------------------------------------------------
// mem fp32 [10000][768] -> memH bf16 [10240][768], padded rows zero.
// ---------------------------------------------------------------------------
__global__ void cvt_memH(const float* __restrict__ mem, unsigned short* __restrict__ dst)
{
    const int m = blockIdx.x;
    const int d = threadIdx.x * 4;
    float4 v = make_float4(0.f, 0.f, 0.f, 0.f);
    if (m < MEMN) v = *(const float4*)&mem[(size_t)m * DIM + d];
    ushort4 o;
    o.x = f2bf(v.x); o.y = f2bf(v.y); o.z = f2bf(v.z); o.w = f2bf(v.w);
    *(ushort4*)&dst[(size_t)m * DIM + d] = o;
}

// ---------------------------------------------------------------------------
// memT bf16 [768][10240]: memT[d][m] = mem[m][d] (0 for m>=10000)
// ---------------------------------------------------------------------------
__global__ void transpose_mem(const float* __restrict__ mem, unsigned short* __restrict__ memT)
{
    __shared__ float T[32][33];
    const int mb = blockIdx.x * 32, db = blockIdx.y * 32;
    const int tx = threadIdx.x & 31, ty = threadIdx.x >> 5;   // ty 0..7
#pragma unroll
    for (int i = 0; i < 4; ++i) {
        int m = mb + ty + 8 * i;
        T[ty + 8 * i][tx] = (m < MEMN) ? mem[(size_t)m * DIM + db + tx] : 0.f;
    }
    __syncthreads();
#pragma unroll
    for (int i = 0; i < 4; ++i) {
        int d = ty + 8 * i;
        memT[(size_t)(db + d) * MEMP + mb + tx] = f2bf(T[tx][d]);
    }
}

// ---------------------------------------------------------------------------
// Fused MFMA attention, 2-way m-split, 512-thread blocks (8 waves).
// XCD-aware swizzle: lb%8 = XCD (round-robin dispatch) -> split=(lb>>2)&1
// puts XCDs 0-3 on split 0, XCDs 4-7 on split 1, so all 64 blocks resident
// on one XCD sweep the SAME m-tiles in the same order (L2-resident,
// 786 KB/tile vs 4 MB L2). This is the round-5 fix for the 915 MB over-fetch.
// ---------------------------------------------------------------------------
__global__ __launch_bounds__(512, 4)
void attn_mfma(const float* __restrict__ Q, const unsigned short* __restrict__ memH,
               const unsigned short* __restrict__ memT,
               float* __restrict__ retrRaw, float* __restrict__ Lvec)
{
    __shared__ __align__(16) unsigned short Qs[32 * 768];   // 48 KB, xor-swizzled
    __shared__ __align__(16) unsigned short Ps[32 * 256];   // 16 KB, xor-swizzled

    const int tid    = threadIdx.x;
    const int w      = tid >> 6;         // wave 0..7
    const int lane   = tid & 63;
    const int quad   = lane >> 4;        // 0..3
    const int l16    = lane & 15;

    // ---- XCD-aware (qi, split) swizzle ----
    const int lb    = blockIdx.x + gridDim.x * blockIdx.y;   // 0..511
    const int split = (lb >> 2) & 1;
    const int qi    = ((lb >> 3) << 2) | (lb & 3);           // 0..255, each once/split
    const int q0    = qi * TQ;

    const int dbase  = w * 96;           // phase-2 d-strip per wave
    const int mstrip = w * 32;           // phase-1 m-strip per wave

    // ---- stage Q tile (fp32 -> bf16, swizzled) once ----
    {
        const int qr  = tid >> 4;            // 0..31
        const int db0 = tid & 15;
        const float* src = Q + (size_t)(q0 + qr) * DIM;
        const int sw = qr & 7;
#pragma unroll
        for (int i = 0; i < 6; ++i) {
            int db = db0 + i * 16;           // 0..95 (blocks of 8 bf16)
            float4 v0 = *(const float4*)&src[db * 8];
            float4 v1 = *(const float4*)&src[db * 8 + 4];
            uint4 o;
            o.x = (unsigned)f2bf(v0.x) | ((unsigned)f2bf(v0.y) << 16);
            o.y = (unsigned)f2bf(v0.z) | ((unsigned)f2bf(v0.w) << 16);
            o.z = (unsigned)f2bf(v1.x) | ((unsigned)f2bf(v1.y) << 16);
            o.w = (unsigned)f2bf(v1.z) | ((unsigned)f2bf(v1.w) << 16);
            *(uint4*)&Qs[qr * 768 + ((db ^ sw) << 3)] = o;
        }
    }
    __syncthreads();

    f32x4 oacc[2][6];
#pragma unroll
    for (int a = 0; a < 2; ++a)
#pragma unroll
        for (int b = 0; b < 6; ++b) oacc[a][b] = (f32x4){0.f, 0.f, 0.f, 0.f};
    float lsum[2][4] = {{0.f, 0.f, 0.f, 0.f}, {0.f, 0.f, 0.f, 0.f}};

    const int xsw = l16 & 7;

    for (int st = 0; st < TILES_PER_SPLIT; ++st) {
        const int m0 = (split * TILES_PER_SPLIT + st) * TM;

        // ---- phase 1: S[32 x 256]; wave w covers m-strip mstrip..+32 ----
        f32x4 sacc[2][2];
#pragma unroll
        for (int a = 0; a < 2; ++a)
#pragma unroll
            for (int b = 0; b < 2; ++b) sacc[a][b] = (f32x4){0.f, 0.f, 0.f, 0.f};

        const unsigned short* brow = memH + (size_t)(m0 + mstrip + l16) * DIM + quad * 8;

        bf16x8 b0 = *(const bf16x8*)(brow);
        bf16x8 b1 = *(const bf16x8*)(brow + 16 * DIM);
        {
            const int xq0 = ((quad) ^ xsw) << 3;
            bf16x8 a0 = *(const bf16x8*)&Qs[l16 * 768 + xq0];
            bf16x8 a1 = *(const bf16x8*)&Qs[(16 + l16) * 768 + xq0];
            for (int kc = 0; kc < DIM - 32; kc += 32) {
                const int nk = kc + 32;
                // prefetch next iteration's fragments
                bf16x8 nb0 = *(const bf16x8*)(brow + nk);
                bf16x8 nb1 = *(const bf16x8*)(brow + 16 * DIM + nk);
                const int xq = (((nk >> 3) + quad) ^ xsw) << 3;
                bf16x8 na0 = *(const bf16x8*)&Qs[l16 * 768 + xq];
                bf16x8 na1 = *(const bf16x8*)&Qs[(16 + l16) * 768 + xq];
                sacc[0][0] = __builtin_amdgcn_mfma_f32_16x16x32_bf16(a0, b0, sacc[0][0], 0, 0, 0);
                sacc[1][0] = __builtin_amdgcn_mfma_f32_16x16x32_bf16(a1, b0, sacc[1][0], 0, 0, 0);
                sacc[0][1] = __builtin_amdgcn_mfma_f32_16x16x32_bf16(a0, b1, sacc[0][1], 0, 0, 0);
                sacc[1][1] = __builtin_amdgcn_mfma_f32_16x16x32_bf16(a1, b1, sacc[1][1], 0, 0, 0);
                a0 = na0; a1 = na1; b0 = nb0; b1 = nb1;
            }
            // peeled last iteration (no wrap prefetch)
            sacc[0][0] = __builtin_amdgcn_mfma_f32_16x16x32_bf16(a0, b0, sacc[0][0], 0, 0, 0);
            sacc[1][0] = __builtin_amdgcn_mfma_f32_16x16x32_bf16(a1, b0, sacc[1][0], 0, 0, 0);
            sacc[0][1] = __builtin_amdgcn_mfma_f32_16x16x32_bf16(a0, b1, sacc[0][1], 0, 0, 0);
            sacc[1][1] = __builtin_amdgcn_mfma_f32_16x16x32_bf16(a1, b1, sacc[1][1], 0, 0, 0);
        }

        __syncthreads();   // barrier A: all waves done reading previous tile's Ps

        // ---- exp + P->LDS (bf16, swizzled) + row-sum accumulation ----
#pragma unroll
        for (int qt = 0; qt < 2; ++qt)
#pragma unroll
            for (int mt = 0; mt < 2; ++mt) {
                const int mloc = mstrip + mt * 16 + l16;      // 0..255
                const bool ok  = (m0 + mloc) < MEMN;
#pragma unroll
                for (int r = 0; r < 4; ++r) {
                    float p = ok ? __expf(sacc[qt][mt][r] * SCALE) : 0.f;
                    const int q = qt * 16 + quad * 4 + r;
                    lsum[qt][r] += p;
                    Ps[q * 256 + (((mloc >> 3) ^ (q & 7)) << 3) + (mloc & 7)] = f2bf(p);
                }
            }

        __syncthreads();   // barrier B: Ps complete

        // ---- phase 2: O += P * Mem; wave w covers d-strip dbase..+96 ----
        const unsigned short* mtp = memT + (size_t)(dbase + l16) * MEMP + m0 + quad * 8;
        bf16x8 c[6];
#pragma unroll
        for (int nt = 0; nt < 6; ++nt)
            c[nt] = *(const bf16x8*)(mtp + (size_t)nt * 16 * MEMP);

        {
            const int xp0 = ((quad) ^ xsw) << 3;
            bf16x8 pa0 = *(const bf16x8*)&Ps[l16 * 256 + xp0];
            bf16x8 pa1 = *(const bf16x8*)&Ps[(16 + l16) * 256 + xp0];
            for (int kc = 0; kc < TM - 32; kc += 32) {
                const int nk = kc + 32;
                const int xp = (((nk >> 3) + quad) ^ xsw) << 3;
                bf16x8 npa0 = *(const bf16x8*)&Ps[l16 * 256 + xp];
                bf16x8 npa1 = *(const bf16x8*)&Ps[(16 + l16) * 256 + xp];
#pragma unroll
                for (int nt = 0; nt < 6; ++nt) {
                    oacc[0][nt] = __builtin_amdgcn_mfma_f32_16x16x32_bf16(pa0, c[nt], oacc[0][nt], 0, 0, 0);
                    oacc[1][nt] = __builtin_amdgcn_mfma_f32_16x16x32_bf16(pa1, c[nt], oacc[1][nt], 0, 0, 0);
                    // reload this slot for the next kc right after its last use
                    c[nt] = *(const bf16x8*)(mtp + (size_t)nt * 16 * MEMP + nk);
                }
                pa0 = npa0; pa1 = npa1;
            }
            // peeled last iteration (no wrap reload)
#pragma unroll
            for (int nt = 0; nt < 6; ++nt) {
                oacc[0][nt] = __builtin_amdgcn_mfma_f32_16x16x32_bf16(pa0, c[nt], oacc[0][nt], 0, 0, 0);
                oacc[1][nt] = __builtin_amdgcn_mfma_f32_16x16x32_bf16(pa1, c[nt], oacc[1][nt], 0, 0, 0);
            }
        }
        // no trailing barrier: next tile's phase 1 doesn't touch Ps
    }

    // ---- epilogue: atomically combine O and L across splits ----
#pragma unroll
    for (int qt = 0; qt < 2; ++qt)
#pragma unroll
        for (int nt = 0; nt < 6; ++nt)
#pragma unroll
            for (int r = 0; r < 4; ++r)
                __hip_atomic_fetch_add(
                    &retrRaw[(size_t)(q0 + qt * 16 + quad * 4 + r) * DIM + dbase + nt * 16 + l16],
                    oacc[qt][nt][r], __ATOMIC_RELAXED, __HIP_MEMORY_SCOPE_AGENT);

#pragma unroll
    for (int qt = 0; qt < 2; ++qt)
#pragma unroll
        for (int r = 0; r < 4; ++r) {
            float v = lsum[qt][r];
#pragma unroll
            for (int off = 1; off < 16; off <<= 1) v += __shfl_xor(v, off);
            if (l16 == 0)
                __hip_atomic_fetch_add(&Lvec[q0 + qt * 16 + quad * 4 + r], v,
                                       __ATOMIC_RELAXED, __HIP_MEMORY_SCOPE_AGENT);
        }
}

// ---------------------------------------------------------------------------
// Normalize retrieved in place + gate. One wave per row.
// ---------------------------------------------------------------------------
__global__ __launch_bounds__(256)
void finalize_gate(float* __restrict__ retr, const float* __restrict__ Lvec,
                   const float* __restrict__ cs, const float* __restrict__ gw,
                   const float* __restrict__ gb, float* __restrict__ gvec)
{
    const int lane = threadIdx.x & 63;
    const int row  = blockIdx.x * 4 + (threadIdx.x >> 6);
    const float rl = 1.0f / Lvec[row];
    float* rr = retr + (size_t)row * DIM;
    const float* cr = cs + (size_t)row * DIM;
    float g = 0.f;
#pragma unroll
    for (int i = 0; i < 12; ++i) {
        int c = lane + 64 * i;
        float r = rr[c] * rl;
        rr[c] = r;
        g += cr[c] * gw[c] + r * gw[DIM + c];
    }
#pragma unroll
    for (int off = 32; off > 0; off >>= 1) g += __shfl_xor(g, off);
    g += gb[0];
    g = 1.0f / (1.0f + __expf(-g));
    if (lane == 0) gvec[row] = g;
}

// ---------------------------------------------------------------------------
__global__ void prep_w1s(const float* __restrict__ w1, float* __restrict__ w1s)
{
    int i = (blockIdx.x * 256 + threadIdx.x) * 4;
    float4 a = *(const float4*)&w1[i];
    float4 b = *(const float4*)&w1[589824 + i];
    *(float4*)&w1s[i] = make_float4(a.x + b.x, a.y + b.y, a.z + b.z, a.w + b.w);
}

// ---------------------------------------------------------------------------
// MLP GEMM (fp32 VALU), tile = 16 rows x 768 cols, 256 threads.
// MODE 0: h = gelu(x@W1s + r@W1c + b1), x = cs + g*r built during staging.
// MODE 1: out = LayerNorm(h@W2 + b2)*gamma + beta (LN fused, wave owns rows).
// ---------------------------------------------------------------------------
template <int MODE>
__global__ __launch_bounds__(256, 2)
void mlp_kernel(const float* __restrict__ A1, const float* __restrict__ W1,
                const float* __restrict__ A2, const float* __restrict__ W2,
                const float* __restrict__ bias, const float* __restrict__ gvec,
                const float* __restrict__ gamma, const float* __restrict__ beta,
                float* __restrict__ out)
{
    __shared__ __align__(16) float As[16][20];
    __shared__ __align__(16) float Ws[16][DIM + 8];

    const int tid = threadIdx.x;
    const int r0  = blockIdx.x * 16;
    const int tq  = tid >> 6;
    const int td  = tid & 63;

    float acc[4][12];
#pragma unroll
    for (int a = 0; a < 4; ++a)
#pragma unroll
        for (int b = 0; b < 12; ++b) acc[a][b] = 0.f;

    const int nsrc = (MODE == 0) ? 2 : 1;
    for (int src = 0; src < nsrc; ++src) {
        const float* A = src ? A2 : A1;
        const float* W = src ? W2 : W1;
        for (int kc = 0; kc < DIM; kc += 16) {
            __syncthreads();
            if (tid < 64) {
                int row = tid >> 2, k4 = (tid & 3) * 4;
                float4 v = *(const float4*)&A[(size_t)(r0 + row) * DIM + kc + k4];
                if (MODE == 0 && src == 0) {
                    float g = gvec[r0 + row];
                    float4 r = *(const float4*)&A2[(size_t)(r0 + row) * DIM + kc + k4];
                    v.x += g * r.x; v.y += g * r.y; v.z += g * r.z; v.w += g * r.w;
                }
                As[k4 + 0][row] = v.x;
                As[k4 + 1][row] = v.y;
                As[k4 + 2][row] = v.z;
                As[k4 + 3][row] = v.w;
            }
#pragma unroll
            for (int i = 0; i < 12; ++i) {
                int f  = tid + i * 256;
                int kr = f / 192;
                int c4 = (f - kr * 192) * 4;
                float4 v = *(const float4*)&W[(size_t)(kc + kr) * DIM + c4];
                *(float4*)&Ws[kr][c4] = v;
            }
            __syncthreads();
#pragma unroll
            for (int k = 0; k < 16; ++k) {
                float4 av = *(const float4*)&As[k][tq * 4];
                float4 w0 = *(const float4*)&Ws[k][td * 12];
                float4 w1 = *(const float4*)&Ws[k][td * 12 + 4];
                float4 w2 = *(const float4*)&Ws[k][td * 12 + 8];
                float aa[4]  = {av.x, av.y, av.z, av.w};
                float ww[12] = {w0.x, w0.y, w0.z, w0.w, w1.x, w1.y, w1.z, w1.w,
                                w2.x, w2.y, w2.z, w2.w};
#pragma unroll
                for (int a = 0; a < 4; ++a)
#pragma unroll
                    for (int b = 0; b < 12; ++b)
                        acc[a][b] += aa[a] * ww[b];
            }
        }
    }

    float4 t0 = *(const float4*)&bias[td * 12];
    float4 t1 = *(const float4*)&bias[td * 12 + 4];
    float4 t2 = *(const float4*)&bias[td * 12 + 8];
    float bv[12] = {t0.x, t0.y, t0.z, t0.w, t1.x, t1.y, t1.z, t1.w, t2.x, t2.y, t2.z, t2.w};

    if (MODE == 0) {
#pragma unroll
        for (int a = 0; a < 4; ++a) {
            int row = r0 + tq * 4 + a;
            float vv[12];
#pragma unroll
            for (int b = 0; b < 12; ++b) {
                float v = acc[a][b] + bv[b];
                vv[b] = 0.5f * v * (1.0f + erff(v * 0.7071067811865476f));
            }
            float* ob = out + (size_t)row * DIM + td * 12;
            *(float4*)(ob)     = make_float4(vv[0], vv[1], vv[2],  vv[3]);
            *(float4*)(ob + 4) = make_float4(vv[4], vv[5], vv[6],  vv[7]);
            *(float4*)(ob + 8) = make_float4(vv[8], vv[9], vv[10], vv[11]);
        }
    } else {
        float4 g0 = *(const float4*)&gamma[td * 12];
        float4 g1 = *(const float4*)&gamma[td * 12 + 4];
        float4 g2 = *(const float4*)&gamma[td * 12 + 8];
        float4 e0 = *(const float4*)&beta[td * 12];
        float4 e1 = *(const float4*)&beta[td * 12 + 4];
        float4 e2 = *(const float4*)&beta[td * 12 + 8];
        float gv[12] = {g0.x, g0.y, g0.z, g0.w, g1.x, g1.y, g1.z, g1.w, g2.x, g2.y, g2.z, g2.w};
        float ev[12] = {e0.x, e0.y, e0.z, e0.w, e1.x, e1.y, e1.z, e1.w, e2.x, e2.y, e2.z, e2.w};
#pragma unroll
        for (int a = 0; a < 4; ++a) {
            float v[12];
            float s1 = 0.f, s2 = 0.f;
#pragma unroll
            for (int b = 0; b < 12; ++b) {
                v[b] = acc[a][b] + bv[b];
                s1 += v[b];
                s2 += v[b] * v[b];
            }
#pragma unroll
            for (int off = 32; off > 0; off >>= 1) {
                s1 += __shfl_xor(s1, off);
                s2 += __shfl_xor(s2, off);
            }
            float mu  = s1 * (1.0f / 768.0f);
            float var = fmaxf(s2 * (1.0f / 768.0f) - mu * mu, 0.f);
            float rs  = rsqrtf(var + 1e-5f);
            int row = r0 + tq * 4 + a;
            float ov[12];
#pragma unroll
            for (int b = 0; b < 12; ++b)
                ov[b] = (v[b] - mu) * rs * gv[b] + ev[b];
            float* ob = out + (size_t)row * DIM + td * 12;
            *(float4*)(ob)     = make_float4(ov[0], ov[1], ov[2],  ov[3]);
            *(float4*)(ob + 4) = make_float4(ov[4], ov[5], ov[6],  ov[7]);
            *(float4*)(ob + 8) = make_float4(ov[8], ov[9], ov[10], ov[11]);
        }
    }
}

// ---------------------------------------------------------------------------
extern "C" void kernel_launch(void* const* d_in, const int* in_sizes, int n_in,
                              void* d_out, int out_size, void* d_ws, size_t ws_size,
                              hipStream_t stream)
{
    const float* cs  = (const float*)d_in[0];
    const float* mem = (const float*)d_in[1];
    const float* gw  = (const float*)d_in[2];
    const float* gb  = (const float*)d_in[3];
    const float* fw1 = (const float*)d_in[4];
    const float* fb1 = (const float*)d_in[5];
    const float* fw2 = (const float*)d_in[6];
    const float* fb2 = (const float*)d_in[7];
    const float* gam = (const float*)d_in[8];
    const float* bet = (const float*)d_in[9];
    float* out = (float*)d_out;

    char* ws = (char*)d_ws;
    // layout (bytes), total ~59 MB (round-4's 59 MB ran clean):
    unsigned short* memH = (unsigned short*)ws;                 // 15,728,640
    unsigned short* memT = (unsigned short*)(ws + 15728640);    // 15,728,640
    float* retr = (float*)(ws + 31457280);                      // 25,165,824 (raw->normalized)
    float* Lvec = (float*)(ws + 56623104);                      // 32,768
    float* gvec = (float*)(ws + 56655872);                      // 32,768
    float* w1s  = (float*)(ws + 56688640);                      // 2,359,296 -> end 59,047,936
    float* hbuf = (float*)ws;   // alias memH+memT (dead after attn), 25.2 MB

    // zero-init atomic accumulation buffers (retr + Lvec are contiguous)
    hipMemsetAsync(retr, 0, (size_t)N_TOK * DIM * 4 + N_TOK * 4, stream);

    cvt_memH<<<MEMP, 192, 0, stream>>>(mem, memH);
    transpose_mem<<<dim3(MEMP / 32, DIM / 32), 256, 0, stream>>>(mem, memT);
    prep_w1s<<<576, 256, 0, stream>>>(fw1, w1s);

    attn_mfma<<<dim3(N_TOK / TQ, NSPLIT), 512, 0, stream>>>(cs, memH, memT, retr, Lvec);
    finalize_gate<<<N_TOK / 4, 256, 0, stream>>>(retr, Lvec, cs, gw, gb, gvec);
    mlp_kernel<0><<<N_TOK / 16, 256, 0, stream>>>(cs, w1s, retr, fw1 + 2 * 589824, fb1,
                                                  gvec, nullptr, nullptr, hbuf);
    mlp_kernel<1><<<N_TOK / 16, 256, 0, stream>>>(hbuf, fw2, nullptr, nullptr, fb2,
                                                  nullptr, gam, bet, out);
}